// Round 1
// baseline (680.480 us; speedup 1.0000x reference)
//
#include <hip/hip_runtime.h>
#include <stdint.h>

// Masker: reproduce JAX threefry RNG (partitionable/fold-like semantics,
// default since jax 0.4.30) to build the per-batch mask, then apply it.
//
// d_out layout: [masked patches: 32*4096*768 f32][mask: 32*4096 f32 (0/1)]

namespace {

constexpr int kB = 32;
constexpr int kN = 4096;
constexpr int kD = 768;
constexpr int kTake = 614;  // int(4096 * 0.15)
constexpr size_t kMaskOff = (size_t)kB * kN * kD;

__device__ __forceinline__ uint32_t rotl32(uint32_t v, int d) {
  return (v << d) | (v >> (32 - d));
}

// JAX threefry-2x32, 20 rounds (jax/_src/prng.py reference impl).
__device__ __forceinline__ void tf2x32(uint32_t k0, uint32_t k1,
                                       uint32_t x0, uint32_t x1,
                                       uint32_t &o0, uint32_t &o1) {
  const uint32_t k2 = k0 ^ k1 ^ 0x1BD11BDAu;
  x0 += k0; x1 += k1;
#define TF_R(r) { x0 += x1; x1 = rotl32(x1, (r)); x1 ^= x0; }
  TF_R(13) TF_R(15) TF_R(26) TF_R(6)   x0 += k1; x1 += k2 + 1u;
  TF_R(17) TF_R(29) TF_R(16) TF_R(24)  x0 += k2; x1 += k0 + 2u;
  TF_R(13) TF_R(15) TF_R(26) TF_R(6)   x0 += k0; x1 += k1 + 3u;
  TF_R(17) TF_R(29) TF_R(16) TF_R(24)  x0 += k1; x1 += k2 + 4u;
  TF_R(13) TF_R(15) TF_R(26) TF_R(6)   x0 += k2; x1 += k0 + 5u;
#undef TF_R
  o0 = x0; o1 = x1;
}

// Partitionable random_bits(key, 32, (n,)): element i = xor of the two
// output words of the threefry block with counter (hi=0, lo=i).
__device__ __forceinline__ uint32_t tf_bits(uint32_t k0, uint32_t k1,
                                            uint32_t i) {
  uint32_t a, b;
  tf2x32(k0, k1, 0u, i, a, b);
  return a ^ b;
}

// In-LDS bitonic sort of 4096 unique uint64 keys, ascending. 1024 threads.
__device__ __forceinline__ void bitonic4096(uint64_t *sk, int tid) {
  for (int k = 2; k <= 4096; k <<= 1) {
    for (int j = k >> 1; j > 0; j >>= 1) {
      __syncthreads();
      const int jm1 = j - 1;
#pragma unroll
      for (int c = tid; c < 2048; c += 1024) {
        const int i = ((c & ~jm1) << 1) | (c & jm1);
        const int p = i | j;
        const uint64_t a = sk[i];
        const uint64_t b = sk[p];
        const bool up = (i & k) == 0;
        if ((a > b) == up) { sk[i] = b; sk[p] = a; }
      }
    }
  }
  __syncthreads();
}

}  // namespace

extern "C" __global__ __launch_bounds__(1024) void masker_mask_kernel(
    float *__restrict__ maskf) {
  __shared__ uint64_t sk[4096];
  __shared__ uint32_t smask[4096];
  const int b = blockIdx.x;
  const int tid = threadIdx.x;

  for (int i = tid; i < kN; i += 1024) smask[i] = 0u;

  // Key chain (all fold-like splits: subkey i = TF(key, (0, i))):
  uint32_t kb0, kb1, kp0, kp1, kr0, kr1, k10, k11, s10, s11, s20, s21;
  tf2x32(0u, 42u, 0u, (uint32_t)b, kb0, kb1);  // keys[b] of split(key(42),32)
  tf2x32(kb0, kb1, 0u, 0u, kp0, kp1);          // k_perm
  tf2x32(kb0, kb1, 0u, 1u, kr0, kr1);          // k_bern
  tf2x32(kp0, kp1, 0u, 0u, k10, k11);          // shuffle round1: carried key
  tf2x32(kp0, kp1, 0u, 1u, s10, s11);          // shuffle round1: subkey
  tf2x32(k10, k11, 0u, 1u, s20, s21);          // shuffle round2: subkey

  // Round 1: stable sort arange(4096) by bits1 -> encode (bits<<12 | idx).
  for (int j = tid; j < kN; j += 1024) {
    const uint32_t bits = tf_bits(s10, s11, (uint32_t)j);
    sk[j] = ((uint64_t)bits << 12) | (uint32_t)j;
  }
  bitonic4096(sk, tid);

  // Round 2: stable sort x1 by bits2, tie-break = current position p.
  // Composite: bits2<<24 | p<<12 | x1[p]  (56 bits, unique).
#pragma unroll
  for (int i = 0; i < 4; ++i) {
    const int p = tid + i * 1024;
    const uint32_t x1v = (uint32_t)(sk[p] & 0xFFFu);
    const uint32_t bits = tf_bits(s20, s21, (uint32_t)p);
    sk[p] = ((uint64_t)bits << 24) | ((uint64_t)p << 12) | x1v;
  }
  bitonic4096(sk, tid);

  // idx = perm[:614]; bern = uniform(k_bern,(614,)) < 0.8; scatter-max.
  if (tid < kTake) {
    const uint32_t v = (uint32_t)(sk[tid] & 0xFFFu);
    const uint32_t ub = tf_bits(kr0, kr1, (uint32_t)tid);
    const float u = __uint_as_float((ub >> 9) | 0x3f800000u) - 1.0f;
    if (u < 0.8f && v != 0u) smask[v] = 1u;
  }
  __syncthreads();

  float *row = maskf + (size_t)b * kN;
  for (int n = tid; n < kN; n += 1024) row[n] = smask[n] ? 1.0f : 0.0f;
}

extern "C" __global__ __launch_bounds__(256) void masker_apply_kernel(
    const float4 *__restrict__ in, float4 *__restrict__ out,
    const float *__restrict__ maskf) {
  const int gid = blockIdx.x * 256 + threadIdx.x;
  const int row = gid / (kD / 4);  // 192 float4 per (b, n) row
  const float m = maskf[row];
  float4 v = in[gid];
  if (m != 0.0f) { v.x = 0.f; v.y = 0.f; v.z = 0.f; v.w = 0.f; }
  out[gid] = v;
}

extern "C" void kernel_launch(void* const* d_in, const int* in_sizes, int n_in,
                              void* d_out, int out_size, void* d_ws,
                              size_t ws_size, hipStream_t stream) {
  (void)in_sizes; (void)n_in; (void)out_size; (void)d_ws; (void)ws_size;
  const float* in = (const float*)d_in[0];
  float* out = (float*)d_out;
  float* maskf = out + kMaskOff;

  masker_mask_kernel<<<kB, 1024, 0, stream>>>(maskf);

  const int n4 = (kB * kN * kD) / 4;          // 25,165,824 float4
  masker_apply_kernel<<<n4 / 256, 256, 0, stream>>>(
      (const float4*)in, (float4*)out, maskf);
}